// Round 11
// baseline (3461.698 us; speedup 1.0000x reference)
//
#include <hip/hip_runtime.h>

typedef __attribute__((ext_vector_type(8))) short bf16x8;
typedef __attribute__((ext_vector_type(4))) float f32x4;
typedef __attribute__((ext_vector_type(2))) _Float16 f16x2;

#define MFMA(a, b, c) __builtin_amdgcn_mfma_f32_16x16x32_bf16((a), (b), (c), 0, 0, 0)
// B operand pinned in AGPR (gfx950 unified file: MFMA reads B from AGPR directly).
// Leading s_nop 1 covers VALU-write->MFMA-read hazards (acc zero-init, any
// allocator v_accvgpr_write copies) that the compiler's hazard recognizer
// cannot see inside asm (R10 post-mortem: missing these nops -> NaN).
#define MFMA_AG(acc, va, ab) \
    asm("s_nop 1\n\tv_mfma_f32_16x16x32_bf16 %0, %1, %2, %0" : "+v"(acc) : "v"(va), "a"(ab))

__device__ __forceinline__ unsigned short f2bf(float f) {
    unsigned int u = __builtin_bit_cast(unsigned int, f);
    return (unsigned short)((u + 0x7FFFu + ((u >> 16) & 1u)) >> 16);  // RNE
}
__device__ __forceinline__ float softplusf(float v) {
    return __logf(1.f + __expf(v));
}

// Prepack to bf16 in ws: dyn h-weights [256 u][256 k] at ws[0..65535],
// W_x [512 out][64 k] at ws[65536..98303].
__global__ __launch_bounds__(256) void prepack_kernel(const float* __restrict__ W_gd,
                                                      unsigned short* __restrict__ ws) {
    int i = blockIdx.x * 256 + threadIdx.x;                     // 0..65535
    ws[i] = f2bf(W_gd[(256 + (i >> 8)) * 320 + 64 + (i & 255)]);
    if (i < 32768) ws[65536 + i] = f2bf(W_gd[(i >> 6) * 320 + (i & 63)]);
}

// B=512, S=128, I=64, H=256, C=10
// 256 blocks (2 batch rows) x 512 threads (8 waves), 1 block/CU.
// Partition: gate+tau weights (128 regs) in AGPRs feeding asm-MFMA B operands
// (tau's 128KB LDS array deleted -> LDS 25->9 reads/stage/wave); dyn chunk0 in
// LDS; dyn chunks 1..7 streamed from L2 via depth-10 register FIFO; A-frags
// hoisted once per stage. L2 stream (112KB/CU/stage ~2150cy) is the floor.
__global__ __launch_bounds__(512, 1)
void ltc_kernel(
    const float* __restrict__ x, const float* __restrict__ W_gd,
    const float* __restrict__ b_gd, const float* __restrict__ W_tau,
    const float* __restrict__ b_tau, const float* __restrict__ gleak,
    const float* __restrict__ cm, const float* __restrict__ W_fc,
    const float* __restrict__ b_fc, const unsigned short* __restrict__ ws,
    float* __restrict__ out)
{
    const int tid  = threadIdx.x;
    const int lane = tid & 63;
    const int wv   = tid >> 6;          // wave 0..7, owns units 32*wv..32*wv+31
    const int c16  = lane & 15;
    const int kg   = lane >> 4;
    const int kg8  = kg * 8;
    const int row0 = blockIdx.x * 2;

    __shared__ __align__(16) unsigned short dynL[4096];        // dyn chunk0, uA-type units
    __shared__ __align__(16) unsigned short abuf[2][2][264];   // ping-pong h_eff [p][row][u]
    __shared__ __align__(16) unsigned short xbuf[2][72];
    __shared__ __align__(8)  float tcL[512];                   // {b_tau, cden}
    __shared__ float bgdL[512];
    __shared__ float hout[2][257];

    // ---- LDS fills ----
    for (int i = tid; i < 4096; i += 512) {                    // uidx = wv*16+c16 <-> u = 32wv+c16
        int uidx = i >> 5, k = i & 31;
        int u = (uidx >> 4) * 32 + (uidx & 15);
        dynL[uidx * 32 + (k ^ ((uidx & 3) << 3))] = f2bf(W_gd[(256 + u) * 320 + 64 + k]);
    }
    for (int i = tid; i < 2 * 2 * 264; i += 512) ((unsigned short*)abuf)[i] = 0;
    if (tid < 256) {
        tcL[2 * tid]     = b_tau[tid];
        tcL[2 * tid + 1] = softplusf(cm[tid]) + softplusf(gleak[tid]) + 1e-6f;
    }
    bgdL[tid] = b_gd[tid];

    const int uA = 32 * wv + c16;
    const int uB = uA + 16;
    const bf16x8* dA0p = (const bf16x8*)(dynL + (wv * 16 + c16) * 32 + (kg8 ^ ((c16 & 3) << 3)));
    const int vOffA = uA * 256 + kg8;       // element offsets into ws
    const int vOffB = vOffA + 16 * 256;
    const int vOffX = 65536 + uA * 64 + kg8;

    // ---- gate + tau weights (used only as "a" asm operands -> AGPR class) ----
    bf16x8 Wg[2][8], Wt[2][8];
    {
        const int wrow[2] = { uA, uB };
        #pragma unroll
        for (int t = 0; t < 2; ++t) {
            const float* gsrc = W_gd + wrow[t] * 320 + 64;
            const float* tsrc = W_tau + wrow[t] * 256;
            #pragma unroll
            for (int s = 0; s < 8; ++s) {
                const float4* gp = (const float4*)(gsrc + s * 32 + kg8);
                const float4* tp = (const float4*)(tsrc + s * 32 + kg8);
                float4 a = gp[0], b = gp[1];
                bf16x8 v;
                v[0] = (short)f2bf(a.x); v[1] = (short)f2bf(a.y);
                v[2] = (short)f2bf(a.z); v[3] = (short)f2bf(a.w);
                v[4] = (short)f2bf(b.x); v[5] = (short)f2bf(b.y);
                v[6] = (short)f2bf(b.z); v[7] = (short)f2bf(b.w);
                Wg[t][s] = v;
                a = tp[0]; b = tp[1];
                v[0] = (short)f2bf(a.x); v[1] = (short)f2bf(a.y);
                v[2] = (short)f2bf(a.z); v[3] = (short)f2bf(a.w);
                v[4] = (short)f2bf(b.x); v[5] = (short)f2bf(b.y);
                v[6] = (short)f2bf(b.z); v[7] = (short)f2bf(b.w);
                Wt[t][s] = v;
            }
        }
    }

    const int rsel = (c16 < 2) ? c16 : 0;
    const unsigned short* aptrP0 = &abuf[0][rsel][kg8];
    const unsigned short* aptrP1 = &abuf[1][rsel][kg8];
    const unsigned short* xptr   = &xbuf[rsel][kg8];

    float hv[2][2] = {{0.f, 0.f}, {0.f, 0.f}};
    f16x2 zh; zh[0] = (_Float16)0.f; zh[1] = (_Float16)0.f;
    f16x2 kk1[2] = { zh, zh }, kk2[2] = { zh, zh }, kk3[2] = { zh, zh };

    // ---- FIFO prologue: window = frags 0..9 (uA s=1..7, uB s=0..2) ----
    bf16x8 pipe[10];
    #pragma unroll
    for (int i = 0; i < 7; ++i)
        pipe[i] = *(const bf16x8*)(ws + vOffA + (i + 1) * 32);
    #pragma unroll
    for (int i = 0; i < 3; ++i)
        pipe[7 + i] = *(const bf16x8*)(ws + vOffB + i * 32);

    __syncthreads();

#define ELEM(ti, G, D, den, en)                                                  \
    _Pragma("unroll")                                                            \
    for (int r = 0; r < 2; ++r) {                                                \
        float gate = G[r] + (float)gdx[ti][r];                                   \
        float dyn  = D[r] + (float)gdx[2 + ti][r];                               \
        float sig = __fdividef(1.f, 1.f + __expf(-gate));                        \
        float th  = 1.f - __fdividef(2.f, __expf(2.f * dyn) + 1.f);              \
        float k1v = (float)kk1[ti][r], k2v = (float)kk2[ti][r], k3v = (float)kk3[ti][r]; \
        float h0 = hv[ti][r];                                                    \
        float ec;                                                                \
        if      (stg == 0) ec = h0;                                              \
        else if (stg == 1) ec = h0 + k1v * (1.f / 3.f);                          \
        else if (stg == 2) ec = h0 - k1v * (1.f / 3.f) + k2v;                    \
        else               ec = h0 + k1v - k2v + k3v;                            \
        float kv = __fdividef(sig * th - ec, den[r]);                            \
        if (stg == 0)      { kk1[ti][r] = (_Float16)kv; en[r] = h0 + kv * (1.f / 3.f); } \
        else if (stg == 1) { kk2[ti][r] = (_Float16)kv; en[r] = h0 - k1v * (1.f / 3.f) + kv; } \
        else if (stg == 2) { kk3[ti][r] = (_Float16)kv; en[r] = h0 + k1v - k2v + kv; } \
        else               { en[r] = h0 + 0.125f * (k1v + 3.f * (k2v + k3v) + kv); hv[ti][r] = en[r]; } \
    }

    #pragma unroll 1
    for (int ts = 0; ts < 128; ++ts) {
        if (tid < 128) {
            int r = tid >> 6, i = tid & 63;
            xbuf[r][i] = f2bf(x[((row0 + r) * 128 + ts) * 64 + i]);
        }
        __syncthreads();

        // ---- x-part GEMM ----
        f32x4 gx0 = {0,0,0,0}, gx1 = {0,0,0,0}, gx2 = {0,0,0,0}, gx3 = {0,0,0,0};
        #pragma unroll
        for (int s = 0; s < 2; ++s) {
            bf16x8 ax = *(const bf16x8*)(xptr + s * 32);
            gx0 = MFMA(ax, *(const bf16x8*)(ws + vOffX + s * 32), gx0);
            gx1 = MFMA(ax, *(const bf16x8*)(ws + vOffX + 16 * 64 + s * 32), gx1);
            gx2 = MFMA(ax, *(const bf16x8*)(ws + vOffX + 256 * 64 + s * 32), gx2);
            gx3 = MFMA(ax, *(const bf16x8*)(ws + vOffX + 272 * 64 + s * 32), gx3);
        }
        f16x2 gdx[4];
        {
            float bg0 = bgdL[uA], bg1 = bgdL[uB], bg2 = bgdL[256 + uA], bg3 = bgdL[256 + uB];
            gdx[0][0] = (_Float16)(gx0[0] + bg0); gdx[0][1] = (_Float16)(gx0[1] + bg0);
            gdx[1][0] = (_Float16)(gx1[0] + bg1); gdx[1][1] = (_Float16)(gx1[1] + bg1);
            gdx[2][0] = (_Float16)(gx2[0] + bg2); gdx[2][1] = (_Float16)(gx2[1] + bg2);
            gdx[3][0] = (_Float16)(gx3[0] + bg3); gdx[3][1] = (_Float16)(gx3[1] + bg3);
        }

        // ---- 4 RK stages; read abuf[stg&1], write abuf[1^(stg&1)], 1 barrier ----
        #pragma unroll
        for (int stg = 0; stg < 4; ++stg) {
            const int p = stg & 1;
            const unsigned short* aptr = p ? aptrP1 : aptrP0;
            unsigned short (*wbuf)[264] = abuf[p ^ 1];

            // A-fragments hoisted: 8 LDS reads per stage (shared by both sweeps)
            bf16x8 Af[8];
            #pragma unroll
            for (int s = 0; s < 8; ++s) Af[s] = *(const bf16x8*)(aptr + s * 32);

            // ---- uA sweep ----
            f32x4 T0 = {0,0,0,0}, G0 = {0,0,0,0}, D0 = {0,0,0,0};
            MFMA_AG(T0, Af[0], Wt[0][0]);
            MFMA_AG(G0, Af[0], Wg[0][0]);
            D0 = MFMA(Af[0], *dA0p, D0);
            #pragma unroll
            for (int s = 1; s < 8; ++s) {
                MFMA_AG(T0, Af[s], Wt[0][s]);
                MFMA_AG(G0, Af[s], Wg[0][s]);
                D0 = MFMA(Af[s], pipe[(s - 1 + 5 * p) % 10], D0);
                // refill consumed slot with frag+10 (window slides)
                if (s <= 5) pipe[(s - 1 + 5 * p) % 10] = *(const bf16x8*)(ws + vOffB + (s + 2) * 32);
                else        pipe[(s - 1 + 5 * p) % 10] = *(const bf16x8*)(ws + vOffA + (s - 5) * 32);
            }
            asm volatile("s_nop 7\n\ts_nop 7\n\ts_nop 7" : "+v"(T0), "+v"(G0));  // MFMA->VALU shield
            float2 tc0 = *(const float2*)(tcL + 2 * uA);
            float den0[2];
            den0[0] = softplusf(T0[0] + tc0.x) + tc0.y;
            den0[1] = softplusf(T0[1] + tc0.x) + tc0.y;
            float en0[2];
            ELEM(0, G0, D0, den0, en0);
            if (lane < 16) { wbuf[0][uA] = f2bf(en0[0]); wbuf[1][uA] = f2bf(en0[1]); }

            // ---- uB sweep (dyn fully streamed) ----
            f32x4 T1 = {0,0,0,0}, G1 = {0,0,0,0}, D1 = {0,0,0,0};
            #pragma unroll
            for (int s = 0; s < 8; ++s) {
                MFMA_AG(T1, Af[s], Wt[1][s]);
                MFMA_AG(G1, Af[s], Wg[1][s]);
                D1 = MFMA(Af[s], pipe[(7 + s + 5 * p) % 10], D1);
                if (s <= 4) pipe[(7 + s + 5 * p) % 10] = *(const bf16x8*)(ws + vOffA + (s + 3) * 32);
                else        pipe[(7 + s + 5 * p) % 10] = *(const bf16x8*)(ws + vOffB + (s - 5) * 32);
            }
            asm volatile("s_nop 7\n\ts_nop 7\n\ts_nop 7" : "+v"(T1), "+v"(G1));
            float2 tc1 = *(const float2*)(tcL + 2 * uB);
            float den1[2];
            den1[0] = softplusf(T1[0] + tc1.x) + tc1.y;
            den1[1] = softplusf(T1[1] + tc1.x) + tc1.y;
            float en1[2];
            ELEM(1, G1, D1, den1, en1);
            if (lane < 16) { wbuf[0][uB] = f2bf(en1[0]); wbuf[1][uB] = f2bf(en1[1]); }

            __syncthreads();   // write-buffer visible; read-buffer never written
        }
    }
#undef ELEM

    // ---- epilogue: out = h @ W_fc^T + b_fc ----
    if (lane < 16) {
        hout[0][uA] = hv[0][0]; hout[1][uA] = hv[0][1];
        hout[0][uB] = hv[1][0]; hout[1][uB] = hv[1][1];
    }
    __syncthreads();
    if (tid < 20) {
        int r = tid / 10, c = tid % 10;
        float acc = b_fc[c];
        for (int k = 0; k < 256; ++k) acc = fmaf(hout[r][k], W_fc[c * 256 + k], acc);
        out[(row0 + r) * 10 + c] = acc;
    }
}

extern "C" void kernel_launch(void* const* d_in, const int* in_sizes, int n_in,
                              void* d_out, int out_size, void* d_ws, size_t ws_size,
                              hipStream_t stream) {
    (void)in_sizes; (void)n_in; (void)out_size; (void)ws_size;
    unsigned short* ws16 = (unsigned short*)d_ws;
    prepack_kernel<<<256, 256, 0, stream>>>((const float*)d_in[1], ws16);
    ltc_kernel<<<256, 512, 0, stream>>>(
        (const float*)d_in[0], (const float*)d_in[1], (const float*)d_in[2],
        (const float*)d_in[3], (const float*)d_in[4], (const float*)d_in[5],
        (const float*)d_in[6], (const float*)d_in[7], (const float*)d_in[8],
        ws16, (float*)d_out);
}

// Round 12
// 911.825 us; speedup vs baseline: 3.7964x; 3.7964x over previous
//
#include <hip/hip_runtime.h>

typedef __attribute__((ext_vector_type(8))) short bf16x8;
typedef __attribute__((ext_vector_type(4))) float f32x4;
typedef __attribute__((ext_vector_type(2))) _Float16 f16x2;

#define MFMA(a, b, c) __builtin_amdgcn_mfma_f32_16x16x32_bf16((a), (b), (c), 0, 0, 0)

__device__ __forceinline__ unsigned short f2bf(float f) {
    unsigned int u = __builtin_bit_cast(unsigned int, f);
    return (unsigned short)((u + 0x7FFFu + ((u >> 16) & 1u)) >> 16);  // RNE
}
__device__ __forceinline__ float softplusf(float v) {
    return __logf(1.f + __expf(v));
}

// Prepack to bf16 in ws: dyn h-weights [256 u][256 k] at ws[0..65535],
// W_x [512 out][64 k] at ws[65536..98303].
__global__ __launch_bounds__(256) void prepack_kernel(const float* __restrict__ W_gd,
                                                      unsigned short* __restrict__ ws) {
    int i = blockIdx.x * 256 + threadIdx.x;                     // 0..65535
    ws[i] = f2bf(W_gd[(256 + (i >> 8)) * 320 + 64 + (i & 255)]);
    if (i < 32768) ws[65536 + i] = f2bf(W_gd[(i >> 6) * 320 + (i & 63)]);
}

// B=512, S=128, I=64, H=256, C=10
// 256 blocks (2 batch rows) x 1024 threads (16 waves), 1 block/CU.
//
// Register law (R1-R11): total regs/lane = 65536/blockDim, no attribute moves
// it; AGPR "a"-constraints don't bypass it (R11: 3.4ms spill disaster). At
// 1024T the budget is 64 regs/lane BUT occupancy is 4 waves/SIMD (R9's 2
// waves/SIMD couldn't overlap the LDS/L2/VALU pipes -> costs summed). Each of
// the 16 waves owns 16 hidden units, so gate weights = 32 regs/lane (fits).
// Partition: gate->regs(32), tau full+dyn chunk0->LDS(144KB, R8-verified
// swizzles), dyn chunks 1..7 -> L2 stream (112KB/stage). Builtin MFMA only.
__global__ __launch_bounds__(1024, 1)
void ltc_kernel(
    const float* __restrict__ x, const float* __restrict__ W_gd,
    const float* __restrict__ b_gd, const float* __restrict__ W_tau,
    const float* __restrict__ b_tau, const float* __restrict__ gleak,
    const float* __restrict__ cm, const float* __restrict__ W_fc,
    const float* __restrict__ b_fc, const unsigned short* __restrict__ ws,
    float* __restrict__ out)
{
    const int tid  = threadIdx.x;
    const int lane = tid & 63;
    const int wv   = tid >> 6;          // wave 0..15, owns units 16*wv..16*wv+15
    const int c16  = lane & 15;
    const int kg   = lane >> 4;
    const int kg8  = kg * 8;
    const int row0 = blockIdx.x * 2;

    __shared__ __align__(16) unsigned short tauL[65536];       // tau, 4-bit XOR swizzle (128 KB)
    __shared__ __align__(16) unsigned short dynL[8192];        // dyn K-chunk0, all 256 units (16 KB)
    __shared__ __align__(16) unsigned short abuf[2][2][264];   // ping-pong h_eff [p][row][u]
    __shared__ __align__(16) unsigned short xbuf[2][72];
    __shared__ __align__(8)  float tcL[512];                   // {b_tau, cden}
    __shared__ float bgdL[512];
    __shared__ float hout[2][257];

    // ---- LDS fills ----
    for (int i = tid; i < 65536; i += 1024) {
        int uu = i >> 8, k = i & 255;
        tauL[uu * 256 + (k ^ ((uu & 15) << 3))] = f2bf(W_tau[i]);
    }
    for (int i = tid; i < 8192; i += 1024) {
        int uu = i >> 5, k = i & 31;
        dynL[uu * 32 + (k ^ ((uu & 3) << 3))] = f2bf(W_gd[(256 + uu) * 320 + 64 + k]);
    }
    for (int i = tid; i < 2 * 2 * 264; i += 1024) ((unsigned short*)abuf)[i] = 0;
    if (tid < 256) {
        tcL[2 * tid]     = b_tau[tid];
        tcL[2 * tid + 1] = softplusf(cm[tid]) + softplusf(gleak[tid]) + 1e-6f;
    }
    if (tid < 512) bgdL[tid] = b_gd[tid];

    const int u = wv * 16 + c16;                 // this lane's hidden unit (column of its tile)
    const int tswz = c16 << 3;                   // tau swizzle key (u&15 == c16)
    const unsigned short* tb = tauL + u * 256;
    const bf16x8* d0p = (const bf16x8*)(dynL + u * 32 + (kg8 ^ ((c16 & 3) << 3)));
    const int vOffD = u * 256 + kg8;             // dyn stream base (elements)
    const int vOffX = 65536 + u * 64 + kg8;      // W_x gate row; dyn row at +16384

    // ---- gate weights into registers: 8 frags = 32 VGPR ----
    bf16x8 Wg[8];
    {
        const float* src = W_gd + u * 320 + 64;
        #pragma unroll
        for (int s = 0; s < 8; ++s) {
            const float4* p = (const float4*)(src + s * 32 + kg8);
            float4 a = p[0], b = p[1];
            bf16x8 v;
            v[0] = (short)f2bf(a.x); v[1] = (short)f2bf(a.y);
            v[2] = (short)f2bf(a.z); v[3] = (short)f2bf(a.w);
            v[4] = (short)f2bf(b.x); v[5] = (short)f2bf(b.y);
            v[6] = (short)f2bf(b.z); v[7] = (short)f2bf(b.w);
            Wg[s] = v;
        }
    }

    const int rsel = (c16 < 2) ? c16 : 0;        // pad rows broadcast row 0 (never consumed)
    const unsigned short* aptrP0 = &abuf[0][rsel][kg8];
    const unsigned short* aptrP1 = &abuf[1][rsel][kg8];
    const unsigned short* xptr   = &xbuf[rsel][kg8];

    // RK state: lane<16 holds rows 0,1 (regs 0,1) of unit u
    float hv[2] = {0.f, 0.f};
    f16x2 zh; zh[0] = (_Float16)0.f; zh[1] = (_Float16)0.f;
    f16x2 kk1 = zh, kk2 = zh, kk3 = zh;

    __syncthreads();

    #pragma unroll 1
    for (int ts = 0; ts < 128; ++ts) {
        if (tid < 128) {
            int r = tid >> 6, i = tid & 63;
            xbuf[r][i] = f2bf(x[((row0 + r) * 128 + ts) * 64 + i]);
        }
        __syncthreads();

        // ---- x-part GEMM (once per step): gate-x and dyn-x for unit u ----
        f32x4 gx0 = {0,0,0,0}, gx1 = {0,0,0,0};
        #pragma unroll
        for (int s = 0; s < 2; ++s) {
            bf16x8 ax = *(const bf16x8*)(xptr + s * 32);
            gx0 = MFMA(ax, *(const bf16x8*)(ws + vOffX + s * 32), gx0);
            gx1 = MFMA(ax, *(const bf16x8*)(ws + vOffX + 16384 + s * 32), gx1);
        }
        f16x2 gdxG, gdxD;
        {
            float bg = bgdL[u], bd = bgdL[256 + u];
            gdxG[0] = (_Float16)(gx0[0] + bg); gdxG[1] = (_Float16)(gx0[1] + bg);
            gdxD[0] = (_Float16)(gx1[0] + bd); gdxD[1] = (_Float16)(gx1[1] + bd);
        }

        // ---- 4 RK stages; read abuf[stg&1], write abuf[1^(stg&1)], 1 barrier ----
        #pragma unroll
        for (int stg = 0; stg < 4; ++stg) {
            const int p = stg & 1;
            const unsigned short* aptr = p ? aptrP1 : aptrP0;
            unsigned short (*wbuf)[264] = abuf[p ^ 1];

            // dyn stream frags for s=1..7 (straight-line; compiler schedules issue)
            bf16x8 Bq[7];
            #pragma unroll
            for (int i = 0; i < 7; ++i)
                Bq[i] = *(const bf16x8*)(ws + vOffD + (i + 1) * 32);

            f32x4 T = {0,0,0,0}, G = {0,0,0,0}, D = {0,0,0,0};
            {
                bf16x8 A = *(const bf16x8*)(aptr);
                T = MFMA(A, *(const bf16x8*)(tb + (kg8 ^ tswz)), T);
                G = MFMA(A, Wg[0], G);
                D = MFMA(A, *d0p, D);
            }
            #pragma unroll
            for (int s = 1; s < 8; ++s) {
                bf16x8 A = *(const bf16x8*)(aptr + s * 32);
                T = MFMA(A, *(const bf16x8*)(tb + ((s * 32 + kg8) ^ tswz)), T);
                G = MFMA(A, Wg[s], G);
                D = MFMA(A, Bq[s - 1], D);
            }

            float2 tc = *(const float2*)(tcL + 2 * u);
            float den0 = softplusf(T[0] + tc.x) + tc.y;
            float den1 = softplusf(T[1] + tc.x) + tc.y;
            float den[2] = { den0, den1 };
            float en[2];
            #pragma unroll
            for (int r = 0; r < 2; ++r) {
                float gate = G[r] + (float)gdxG[r];
                float dyn  = D[r] + (float)gdxD[r];
                float sig = __fdividef(1.f, 1.f + __expf(-gate));
                float th  = 1.f - __fdividef(2.f, __expf(2.f * dyn) + 1.f);
                float k1v = (float)kk1[r], k2v = (float)kk2[r], k3v = (float)kk3[r];
                float h0 = hv[r];
                float ec;
                if      (stg == 0) ec = h0;
                else if (stg == 1) ec = h0 + k1v * (1.f / 3.f);
                else if (stg == 2) ec = h0 - k1v * (1.f / 3.f) + k2v;
                else               ec = h0 + k1v - k2v + k3v;
                float kv = __fdividef(sig * th - ec, den[r]);
                if (stg == 0)      { kk1[r] = (_Float16)kv; en[r] = h0 + kv * (1.f / 3.f); }
                else if (stg == 1) { kk2[r] = (_Float16)kv; en[r] = h0 - k1v * (1.f / 3.f) + kv; }
                else if (stg == 2) { kk3[r] = (_Float16)kv; en[r] = h0 + k1v - k2v + kv; }
                else               { en[r] = h0 + 0.125f * (k1v + 3.f * (k2v + k3v) + kv); hv[r] = en[r]; }
            }
            if (lane < 16) { wbuf[0][u] = f2bf(en[0]); wbuf[1][u] = f2bf(en[1]); }

            __syncthreads();   // write-buffer visible; read-buffer never written
        }
    }

    // ---- epilogue: out = h @ W_fc^T + b_fc ----
    if (lane < 16) { hout[0][u] = hv[0]; hout[1][u] = hv[1]; }
    __syncthreads();
    if (tid < 20) {
        int r = tid / 10, c = tid % 10;
        float acc = b_fc[c];
        for (int k = 0; k < 256; ++k) acc = fmaf(hout[r][k], W_fc[c * 256 + k], acc);
        out[(row0 + r) * 10 + c] = acc;
    }
}

extern "C" void kernel_launch(void* const* d_in, const int* in_sizes, int n_in,
                              void* d_out, int out_size, void* d_ws, size_t ws_size,
                              hipStream_t stream) {
    (void)in_sizes; (void)n_in; (void)out_size; (void)ws_size;
    unsigned short* ws16 = (unsigned short*)d_ws;
    prepack_kernel<<<256, 256, 0, stream>>>((const float*)d_in[1], ws16);
    ltc_kernel<<<256, 1024, 0, stream>>>(
        (const float*)d_in[0], (const float*)d_in[1], (const float*)d_in[2],
        (const float*)d_in[3], (const float*)d_in[4], (const float*)d_in[5],
        (const float*)d_in[6], (const float*)d_in[7], (const float*)d_in[8],
        ws16, (float*)d_out);
}